// Round 1
// baseline (3403.115 us; speedup 1.0000x reference)
//
#include <hip/hip_runtime.h>
#include <cstdint>

#define D 300
#define MAXLEN 50
#define K1P 320    // padded K for gemm1 (agg cols)
#define H1 600     // hidden dim
#define H1P 608    // padded hidden (gemm2 K)
#define W1ROWS 640 // padded Nout rows for W1t (5 col-tiles of 128)
#define W2ROWS 384 // padded Nout rows for W2t (3 col-tiles of 128)

typedef __attribute__((ext_vector_type(8))) short s16x8;
typedef __attribute__((ext_vector_type(4))) float f32x4;

__device__ __forceinline__ unsigned short f2b(float f) {
  uint32_t u = __builtin_bit_cast(uint32_t, f);
  u += 0x7FFFu + ((u >> 16) & 1u);
  return (unsigned short)(u >> 16);
}

__device__ __forceinline__ void gld_lds16(const void* g, void* l) {
  __builtin_amdgcn_global_load_lds((const __attribute__((address_space(1))) void*)g,
                                   (__attribute__((address_space(3))) void*)l, 16, 0, 0);
}

// ---------------- embedding: h0 = x_emb1[x0] + x_emb2[x1] ----------------
__global__ void k_embed(const int* __restrict__ x, const float* __restrict__ xe1,
                        const float* __restrict__ xe2, float* __restrict__ h, int n4) {
  int i = blockIdx.x * blockDim.x + threadIdx.x;
  if (i >= n4) return;
  int base = i * 4;
  int row = base / D;
  int d = base - row * D;
  int a = x[2 * row], b = x[2 * row + 1];
  const float* p1 = xe1 + (size_t)a * D + d;
  const float* p2 = xe2 + (size_t)b * D + d;
  f32x4 v;
#pragma unroll
  for (int k = 0; k < 4; ++k) v[k] = p1[k] + p2[k];
  *(f32x4*)(h + base) = v;
}

// zero the K-pad columns of aggbf [N][320] (cols 300..319) and hid [N][608] (cols 600..607)
__global__ void k_padfill(unsigned short* __restrict__ aggbf, unsigned short* __restrict__ hid, int N) {
  int idx = blockIdx.x * blockDim.x + threadIdx.x;
  if (idx >= N * 28) return;
  int i = idx / 28, j = idx - i * 28;
  if (j < 20) aggbf[(size_t)i * K1P + D + j] = 0;
  else        hid[(size_t)i * H1P + H1 + (j - 20)] = 0;
}

__global__ void k_count(const int* __restrict__ key, int* __restrict__ cnt, int n) {
  int i = blockIdx.x * blockDim.x + threadIdx.x;
  if (i < n) atomicAdd(&cnt[key[i]], 1);
}

// single-block exclusive scan, out[n] = total
__global__ void k_exscan(const int* __restrict__ in, int* __restrict__ out, int n) {
  __shared__ int smem[1024];
  int tid = threadIdx.x;
  int chunk = (n + 1023) >> 10;
  int beg = tid * chunk;
  int end = beg + chunk; if (end > n) end = n;
  int s = 0;
  for (int i = beg; i < end; ++i) s += in[i];
  smem[tid] = s;
  __syncthreads();
  for (int off = 1; off < 1024; off <<= 1) {
    int v = (tid >= off) ? smem[tid - off] : 0;
    __syncthreads();
    smem[tid] += v;
    __syncthreads();
  }
  int run = smem[tid] - s;
  for (int i = beg; i < end; ++i) { out[i] = run; run += in[i]; }
  if (tid == 1023) out[n] = smem[1023];
}

__global__ void k_fill(const int* __restrict__ dst, int* __restrict__ cur,
                       const int* __restrict__ offs, int* __restrict__ sorted, int E_) {
  int e = blockIdx.x * blockDim.x + threadIdx.x;
  if (e >= E_) return;
  int d = dst[e];
  int p = atomicAdd(&cur[d], 1);
  sorted[offs[d] + p] = e;
}

// ---------------- aggregation: one wave per node; CSR gather-sum -> bf16 ----------------
__global__ void k_agg(const float* __restrict__ h, const int* __restrict__ src,
                      const int* __restrict__ ea, const int* __restrict__ offs,
                      const int* __restrict__ sorted, const float* __restrict__ e1,
                      const float* __restrict__ e2, unsigned short* __restrict__ aggbf, int N) {
  int w = (int)((blockIdx.x * blockDim.x + threadIdx.x) >> 6);
  if (w >= N) return;
  int lane = threadIdx.x & 63;
  int beg = offs[w], end = offs[w + 1];
  float s[5];
#pragma unroll
  for (int i = 0; i < 5; ++i) {
    int d = i * 64 + lane;
    s[i] = (d < D) ? (h[(size_t)w * D + d] + e1[4 * D + d] + e2[d]) : 0.f;  // self loop: bond=4, dir=0
  }
  for (int j = beg; j < end; ++j) {
    int e = sorted[j];
    int sv = src[e];
    int a0 = ea[2 * e], a1 = ea[2 * e + 1];
    const float* hp = h + (size_t)sv * D;
    const float* t1 = e1 + (size_t)a0 * D;
    const float* t2 = e2 + (size_t)a1 * D;
#pragma unroll
    for (int i = 0; i < 5; ++i) {
      int d = i * 64 + lane;
      if (d < D) s[i] += hp[d] + t1[d] + t2[d];
    }
  }
#pragma unroll
  for (int i = 0; i < 5; ++i) {
    int d = i * 64 + lane;
    if (d < D) aggbf[(size_t)w * K1P + d] = f2b(s[i]);
  }
}

// transpose+convert weights: Wt[n][k] = bf16(W[k][n]), zero-padded
__global__ void k_wconv(const float* __restrict__ W, unsigned short* __restrict__ Wt,
                        int K, int Nout, int Kp, int total) {
  int idx = blockIdx.x * blockDim.x + threadIdx.x;
  if (idx >= total) return;
  int n = idx / Kp, k = idx - n * Kp;
  float v = (k < K && n < Nout) ? W[(size_t)k * Nout + n] : 0.f;
  Wt[idx] = f2b(v);
}

// ---------------- bf16 MFMA GEMM: C[M][Nout] = A[M][K] * Bt[n][k]^T + bias ----------------
// 128x128 tile, BK=32, 4 waves (2x2), global_load_lds staging.
// EPI=1: relu -> bf16 store to Cb (ldc); EPI=0: f32 store to Cf (ldc).
template <int K, int EPI>
__global__ __launch_bounds__(256) void k_gemm(const unsigned short* __restrict__ A,
                                              const unsigned short* __restrict__ Bt,
                                              const float* __restrict__ bias,
                                              unsigned short* __restrict__ Cb,
                                              float* __restrict__ Cf,
                                              int M, int Nout, int ldc) {
  __shared__ __align__(16) unsigned short Alds[4 * 128 * 8];
  __shared__ __align__(16) unsigned short Blds[4 * 128 * 8];
  const int tid = threadIdx.x, lane = tid & 63, wave = tid >> 6;
  const int wm = wave >> 1, wn = wave & 1;
  const int rowBase = blockIdx.y * 128, colBase = blockIdx.x * 128;
  const int l15 = lane & 15, lg = lane >> 4;
  f32x4 acc[4][4] = {};
  for (int k0 = 0; k0 < K; k0 += 32) {
#pragma unroll
    for (int i = 0; i < 2; ++i) {
      int c = tid + i * 256;
      int kg = c >> 7, r = c & 127;
      int gr = rowBase + r; if (gr >= M) gr = M - 1;
      gld_lds16(A + (size_t)gr * K + (k0 + kg * 8), Alds + (size_t)c * 8);
      gld_lds16(Bt + (size_t)(colBase + r) * K + (k0 + kg * 8), Blds + (size_t)c * 8);
    }
    __syncthreads();
    s16x8 af[4], bf[4];
#pragma unroll
    for (int i = 0; i < 4; ++i) {
      af[i] = *(const s16x8*)(Alds + ((size_t)lg * 128 + wm * 64 + i * 16 + l15) * 8);
      bf[i] = *(const s16x8*)(Blds + ((size_t)lg * 128 + wn * 64 + i * 16 + l15) * 8);
    }
#pragma unroll
    for (int mi = 0; mi < 4; ++mi)
#pragma unroll
      for (int ni = 0; ni < 4; ++ni)
        acc[mi][ni] = __builtin_amdgcn_mfma_f32_16x16x32_bf16(af[mi], bf[ni], acc[mi][ni], 0, 0, 0);
    __syncthreads();
  }
#pragma unroll
  for (int mi = 0; mi < 4; ++mi) {
    int row0 = rowBase + wm * 64 + mi * 16 + lg * 4;
#pragma unroll
    for (int ni = 0; ni < 4; ++ni) {
      int col = colBase + wn * 64 + ni * 16 + l15;
      if (col < Nout) {
        float bv = bias[col];
#pragma unroll
        for (int r = 0; r < 4; ++r) {
          int rr = row0 + r;
          if (rr < M) {
            float v = acc[mi][ni][r] + bv;
            if (EPI) { v = fmaxf(v, 0.f); Cb[(size_t)rr * ldc + col] = f2b(v); }
            else     { Cf[(size_t)rr * ldc + col] = v; }
          }
        }
      }
    }
  }
}

// ---------------- BatchNorm ----------------
__global__ void k_bnstats(const float* __restrict__ h2, float* __restrict__ sums,
                          float* __restrict__ sumsq, int N) {
  int c = threadIdx.x;
  if (c >= D) return;
  int r0 = blockIdx.x * 256;
  int r1 = r0 + 256; if (r1 > N) r1 = N;
  float s = 0.f, q = 0.f;
  for (int r = r0; r < r1; ++r) {
    float v = h2[(size_t)r * D + c];
    s += v; q += v * v;
  }
  atomicAdd(&sums[c], s);
  atomicAdd(&sumsq[c], q);
}

__global__ void k_bnfinal(const float* __restrict__ sums, const float* __restrict__ sumsq,
                          const float* __restrict__ gamma, const float* __restrict__ beta,
                          float* __restrict__ scale, float* __restrict__ shift, int N) {
  int c = threadIdx.x;
  if (c >= D) return;
  float inv = 1.f / (float)N;
  float mean = sums[c] * inv;
  float var = sumsq[c] * inv - mean * mean;
  if (var < 0.f) var = 0.f;
  float sc = gamma[c] * rsqrtf(var + 1e-5f);
  scale[c] = sc;
  shift[c] = beta[c] - mean * sc;
}

__global__ void k_bnnorm(const float* __restrict__ h2, const float* __restrict__ scale,
                         const float* __restrict__ shift, float* __restrict__ h, int n4, int relu) {
  int i = blockIdx.x * blockDim.x + threadIdx.x;
  if (i >= n4) return;
  int base = i * 4;
  int d = base % D;
  f32x4 v = *(const f32x4*)(h2 + base);
#pragma unroll
  for (int k = 0; k < 4; ++k) {
    float xv = v[k] * scale[d + k] + shift[d + k];
    if (relu) xv = fmaxf(xv, 0.f);
    v[k] = xv;
  }
  *(f32x4*)(h + base) = v;
}

// ---------------- outputs ----------------
__global__ void k_pool(const float* __restrict__ h, const int* __restrict__ gs,
                       const int* __restrict__ gc, float* __restrict__ pooled) {
  int g = blockIdx.x, c = threadIdx.x;
  if (c >= D) return;
  int start = gs[g], cnt = gc[g];
  float s = 0.f;
  for (int i = 0; i < cnt; ++i) s += h[(size_t)(start + i) * D + c];
  int dv = cnt > 0 ? cnt : 1;
  pooled[(size_t)g * D + c] = s / (float)dv;
}

__global__ void k_nf(const float* __restrict__ h, const int* __restrict__ gs,
                     const int* __restrict__ gc, float* __restrict__ nf, float* __restrict__ mask) {
  int g = blockIdx.x;
  int start = gs[g], cnt = gc[g];
  int lim = cnt < MAXLEN ? cnt : MAXLEN;
  for (int idx = threadIdx.x; idx < MAXLEN * D; idx += 256) {
    int p = idx / D;
    int c = idx - p * D;
    float v = (p < lim) ? h[(size_t)(start + p) * D + c] : 0.f;
    nf[(size_t)g * (MAXLEN * D) + idx] = v;
  }
  if (threadIdx.x < MAXLEN) mask[(size_t)g * MAXLEN + threadIdx.x] = (threadIdx.x < lim) ? 1.f : 0.f;
}

extern "C" void kernel_launch(void* const* d_in, const int* in_sizes, int n_in,
                              void* d_out, int out_size, void* d_ws, size_t ws_size,
                              hipStream_t stream) {
  const int* x      = (const int*)d_in[0];
  const int* ei     = (const int*)d_in[1];   // [2][E]: src = ei, dst = ei+E
  const int* ea     = (const int*)d_in[2];   // [E][2]
  const int* batch  = (const int*)d_in[3];
  const float* xe1  = (const float*)d_in[5];
  const float* xe2  = (const float*)d_in[6];
  const float* ee1  = (const float*)d_in[7]; // [L][6][D]
  const float* ee2  = (const float*)d_in[8]; // [L][3][D]
  const float* W1   = (const float*)d_in[9];
  const float* b1   = (const float*)d_in[10];
  const float* W2   = (const float*)d_in[11];
  const float* b2   = (const float*)d_in[12];
  const float* gamma = (const float*)d_in[13];
  const float* beta  = (const float*)d_in[14];

  const int N = in_sizes[0] / 2;
  const int E = in_sizes[1] / 2;
  const int L = in_sizes[9] / (D * 2 * D);
  const int B = out_size / (D + MAXLEN * D + MAXLEN);

  char* ws = (char*)d_ws;
  size_t off = 0;
  auto alloc = [&](size_t bytes) -> void* {
    void* p = ws + off;
    off += (bytes + 255) & ~(size_t)255;
    return p;
  };
  float* h   = (float*)alloc((size_t)N * D * 4);
  float* h2  = (float*)alloc((size_t)N * D * 4);
  unsigned short* aggbf = (unsigned short*)alloc((size_t)N * K1P * 2);
  unsigned short* hid   = (unsigned short*)alloc((size_t)N * H1P * 2);
  unsigned short* W1t = (unsigned short*)alloc((size_t)W1ROWS * K1P * 2);
  unsigned short* W2t = (unsigned short*)alloc((size_t)W2ROWS * H1P * 2);
  int* cnt    = (int*)alloc((size_t)N * 4);
  int* cur    = (int*)alloc((size_t)N * 4);
  int* offs   = (int*)alloc((size_t)(N + 1) * 4);
  int* sorted = (int*)alloc((size_t)E * 4);
  int* gc     = (int*)alloc((size_t)B * 4);
  int* gs     = (int*)alloc((size_t)(B + 1) * 4);
  float* sums  = (float*)alloc(2 * D * 4);  // sums | sumsq
  float* scale = (float*)alloc(2 * D * 4);  // scale | shift

  hipMemsetAsync(cnt, 0, (size_t)N * 4, stream);
  hipMemsetAsync(cur, 0, (size_t)N * 4, stream);
  hipMemsetAsync(gc, 0, (size_t)B * 4, stream);

  const int n4 = N * D / 4;
  k_embed<<<(n4 + 255) / 256, 256, 0, stream>>>(x, xe1, xe2, h, n4);
  k_padfill<<<(N * 28 + 255) / 256, 256, 0, stream>>>(aggbf, hid, N);
  k_count<<<(E + 255) / 256, 256, 0, stream>>>(ei + E, cnt, E);
  k_exscan<<<1, 1024, 0, stream>>>(cnt, offs, N);
  k_fill<<<(E + 255) / 256, 256, 0, stream>>>(ei + E, cur, offs, sorted, E);
  k_count<<<(N + 255) / 256, 256, 0, stream>>>(batch, gc, N);
  k_exscan<<<1, 1024, 0, stream>>>(gc, gs, B);

  const int rowTiles = (N + 127) / 128;
  for (int l = 0; l < L; ++l) {
    k_wconv<<<(W1ROWS * K1P + 255) / 256, 256, 0, stream>>>(W1 + (size_t)l * D * H1, W1t, D, H1, K1P, W1ROWS * K1P);
    k_wconv<<<(W2ROWS * H1P + 255) / 256, 256, 0, stream>>>(W2 + (size_t)l * H1 * D, W2t, H1, D, H1P, W2ROWS * H1P);
    k_agg<<<(N + 3) / 4, 256, 0, stream>>>(h, ei, ea, offs, sorted,
                                           ee1 + (size_t)l * 6 * D, ee2 + (size_t)l * 3 * D, aggbf, N);
    k_gemm<K1P, 1><<<dim3(5, rowTiles), 256, 0, stream>>>(aggbf, W1t, b1 + (size_t)l * H1, hid, nullptr, N, H1, H1P);
    k_gemm<H1P, 0><<<dim3(3, rowTiles), 256, 0, stream>>>(hid, W2t, b2 + (size_t)l * D, nullptr, h2, N, D, D);
    hipMemsetAsync(sums, 0, 2 * D * 4, stream);
    k_bnstats<<<(N + 255) / 256, 320, 0, stream>>>(h2, sums, sums + D, N);
    k_bnfinal<<<1, 320, 0, stream>>>(sums, sums + D, gamma + (size_t)l * D, beta + (size_t)l * D, scale, scale + D, N);
    k_bnnorm<<<(n4 + 255) / 256, 256, 0, stream>>>(h2, scale, scale + D, h, n4, (l != L - 1) ? 1 : 0);
  }

  float* out = (float*)d_out;
  float* out_pooled = out;
  float* out_nf = out + (size_t)B * D;
  float* out_mask = out + (size_t)B * D + (size_t)B * MAXLEN * D;
  k_pool<<<B, 320, 0, stream>>>(h, gs, gc, out_pooled);
  k_nf<<<B, 256, 0, stream>>>(h, gs, gc, out_nf, out_mask);
}

// Round 2
// 3034.704 us; speedup vs baseline: 1.1214x; 1.1214x over previous
//
#include <hip/hip_runtime.h>
#include <cstdint>

#define D 300
#define MAXLEN 50
#define K1P 320    // padded K for gemm1 (agg cols)
#define H1 600     // hidden dim
#define H1P 608    // padded hidden (gemm2 K)
#define W1ROWS 640 // padded Nout rows for W1t (5 col-tiles of 128)
#define W2ROWS 384 // padded Nout rows for W2t (3 col-tiles of 128)

typedef __attribute__((ext_vector_type(8))) short s16x8;
typedef __attribute__((ext_vector_type(4))) float f32x4;

__device__ __forceinline__ unsigned short f2b(float f) {
  uint32_t u = __builtin_bit_cast(uint32_t, f);
  u += 0x7FFFu + ((u >> 16) & 1u);
  return (unsigned short)(u >> 16);
}

// ---------------- embedding: h0 = x_emb1[x0] + x_emb2[x1] ----------------
__global__ void k_embed(const int* __restrict__ x, const float* __restrict__ xe1,
                        const float* __restrict__ xe2, float* __restrict__ h, int n4) {
  int i = blockIdx.x * blockDim.x + threadIdx.x;
  if (i >= n4) return;
  int base = i * 4;
  int row = base / D;
  int d = base - row * D;
  int a = x[2 * row], b = x[2 * row + 1];
  const float* p1 = xe1 + (size_t)a * D + d;
  const float* p2 = xe2 + (size_t)b * D + d;
  f32x4 v;
#pragma unroll
  for (int k = 0; k < 4; ++k) v[k] = p1[k] + p2[k];
  *(f32x4*)(h + base) = v;
}

// zero the K-pad columns of aggbf [N][320] (cols 300..319) and hid [N][608] (cols 600..607)
__global__ void k_padfill(unsigned short* __restrict__ aggbf, unsigned short* __restrict__ hid, int N) {
  int idx = blockIdx.x * blockDim.x + threadIdx.x;
  if (idx >= N * 28) return;
  int i = idx / 28, j = idx - i * 28;
  if (j < 20) aggbf[(size_t)i * K1P + D + j] = 0;
  else        hid[(size_t)i * H1P + H1 + (j - 20)] = 0;
}

__global__ void k_count(const int* __restrict__ key, int* __restrict__ cnt, int n) {
  int i = blockIdx.x * blockDim.x + threadIdx.x;
  if (i < n) atomicAdd(&cnt[key[i]], 1);
}

// single-block exclusive scan, out[n] = total
__global__ void k_exscan(const int* __restrict__ in, int* __restrict__ out, int n) {
  __shared__ int smem[1024];
  int tid = threadIdx.x;
  int chunk = (n + 1023) >> 10;
  int beg = tid * chunk;
  int end = beg + chunk; if (end > n) end = n;
  int s = 0;
  for (int i = beg; i < end; ++i) s += in[i];
  smem[tid] = s;
  __syncthreads();
  for (int off = 1; off < 1024; off <<= 1) {
    int v = (tid >= off) ? smem[tid - off] : 0;
    __syncthreads();
    smem[tid] += v;
    __syncthreads();
  }
  int run = smem[tid] - s;
  for (int i = beg; i < end; ++i) { out[i] = run; run += in[i]; }
  if (tid == 1023) out[n] = smem[1023];
}

// fill dst-sorted src node ids and edge-emb combo ids
__global__ void k_fill(const int* __restrict__ src, const int* __restrict__ dst,
                       const int* __restrict__ ea, int* __restrict__ cur,
                       const int* __restrict__ offs, int* __restrict__ ssrc,
                       int* __restrict__ seco, int E_) {
  int e = blockIdx.x * blockDim.x + threadIdx.x;
  if (e >= E_) return;
  int d = dst[e];
  int p = atomicAdd(&cur[d], 1);
  int pos = offs[d] + p;
  ssrc[pos] = src[e];
  seco[pos] = ea[2 * e] * 3 + ea[2 * e + 1];
}

// combined edge-emb table: ec[l][c0*3+c1][d] = e1[l][c0][d] + e2[l][c1][d]
__global__ void k_ecomb(const float* __restrict__ e1, const float* __restrict__ e2,
                        float* __restrict__ ec, int total /* L*18*D */) {
  int i = blockIdx.x * blockDim.x + threadIdx.x;
  if (i >= total) return;
  int d = i % D;
  int c = (i / D) % 18;
  int l = i / (18 * D);
  int c0 = c / 3, c1 = c - c0 * 3;
  ec[i] = e1[((size_t)l * 6 + c0) * D + d] + e2[((size_t)l * 3 + c1) * D + d];
}

// ---------------- aggregation: one wave per node; CSR gather-sum -> bf16 ----------------
__global__ void k_agg(const float* __restrict__ h, const int* __restrict__ ssrc,
                      const int* __restrict__ seco, const int* __restrict__ offs,
                      const float* __restrict__ ec, unsigned short* __restrict__ aggbf, int N) {
  int w = (int)((blockIdx.x * blockDim.x + threadIdx.x) >> 6);
  if (w >= N) return;
  int lane = threadIdx.x & 63;
  int beg = offs[w], end = offs[w + 1];
  float s[5];
#pragma unroll
  for (int i = 0; i < 5; ++i) {
    int d = i * 64 + lane;
    s[i] = (d < D) ? (h[(size_t)w * D + d] + ec[12 * D + d]) : 0.f;  // self loop: bond=4,dir=0 -> combo 12
  }
  for (int j = beg; j < end; ++j) {
    int sv = ssrc[j];
    int co = seco[j];
    const float* hp = h + (size_t)sv * D;
    const float* tp = ec + (size_t)co * D;
#pragma unroll
    for (int i = 0; i < 5; ++i) {
      int d = i * 64 + lane;
      if (d < D) s[i] += hp[d] + tp[d];
    }
  }
#pragma unroll
  for (int i = 0; i < 5; ++i) {
    int d = i * 64 + lane;
    if (d < D) aggbf[(size_t)w * K1P + d] = f2b(s[i]);
  }
}

// transpose+convert weights: Wt[n][k] = bf16(W[k][n]), zero-padded
__global__ void k_wconv(const float* __restrict__ W, unsigned short* __restrict__ Wt,
                        int K, int Nout, int Kp, int total) {
  int idx = blockIdx.x * blockDim.x + threadIdx.x;
  if (idx >= total) return;
  int n = idx / Kp, k = idx - n * Kp;
  float v = (k < K && n < Nout) ? W[(size_t)k * Nout + n] : 0.f;
  Wt[idx] = f2b(v);
}

// ---------------- no-LDS streaming bf16 MFMA GEMM ----------------
// C[M][Nout] = A[M][K] * Bt[n][k]^T + bias. 128x128 block tile, 4 waves (2x2),
// fragments loaded straight from global (A rows / Bt rows are contiguous in k).
// EPI=1: relu -> bf16 store; EPI=0: f32 store + fused BN column stats (sums, sumsq).
template <int K, int EPI>
__global__ __launch_bounds__(256) void k_gemm(const unsigned short* __restrict__ A,
                                              const unsigned short* __restrict__ Bt,
                                              const float* __restrict__ bias,
                                              unsigned short* __restrict__ Cb,
                                              float* __restrict__ Cf,
                                              float* __restrict__ sums,
                                              int M, int Nout, int ldc, int CT) {
  // bijective XCD-chunk swizzle: consecutive wg (col-tiles of one row-panel) -> same XCD
  int nwg = gridDim.x, orig = blockIdx.x;
  int q = nwg >> 3, r = nwg & 7;
  int xcd = orig & 7, idx = orig >> 3;
  int wg = (xcd < r) ? (xcd * (q + 1) + idx) : (r * (q + 1) + (xcd - r) * q + idx);
  int ct = wg % CT, rt = wg / CT;

  const int tid = threadIdx.x, lane = tid & 63, wave = tid >> 6;
  const int wm = wave >> 1, wn = wave & 1;
  const int rowBase = rt * 128, colBase = ct * 128;
  const int l15 = lane & 15, lg = lane >> 4;

  const unsigned short* Ap[4];
  const unsigned short* Bp[4];
#pragma unroll
  for (int mi = 0; mi < 4; ++mi) {
    int rr = rowBase + wm * 64 + mi * 16 + l15;
    if (rr >= M) rr = M - 1;
    Ap[mi] = A + (size_t)rr * K + lg * 8;
  }
#pragma unroll
  for (int ni = 0; ni < 4; ++ni) {
    int cc = colBase + wn * 64 + ni * 16 + l15;  // Bt padded to CT*128 rows
    Bp[ni] = Bt + (size_t)cc * K + lg * 8;
  }

  f32x4 acc[4][4] = {};
#pragma unroll
  for (int t = 0; t < K / 32; ++t) {
    s16x8 af[4], bf[4];
#pragma unroll
    for (int mi = 0; mi < 4; ++mi) af[mi] = *(const s16x8*)(Ap[mi] + t * 32);
#pragma unroll
    for (int ni = 0; ni < 4; ++ni) bf[ni] = *(const s16x8*)(Bp[ni] + t * 32);
#pragma unroll
    for (int mi = 0; mi < 4; ++mi)
#pragma unroll
      for (int ni = 0; ni < 4; ++ni)
        acc[mi][ni] = __builtin_amdgcn_mfma_f32_16x16x32_bf16(af[mi], bf[ni], acc[mi][ni], 0, 0, 0);
  }

#pragma unroll
  for (int ni = 0; ni < 4; ++ni) {
    int col = colBase + wn * 64 + ni * 16 + l15;
    if (col >= Nout) continue;
    float bv = bias[col];
    float cs = 0.f, cq = 0.f;
#pragma unroll
    for (int mi = 0; mi < 4; ++mi) {
      int row0 = rowBase + wm * 64 + mi * 16 + lg * 4;
#pragma unroll
      for (int rr = 0; rr < 4; ++rr) {
        int row = row0 + rr;
        if (row < M) {
          float v = acc[mi][ni][rr] + bv;
          if (EPI) {
            v = fmaxf(v, 0.f);
            Cb[(size_t)row * ldc + col] = f2b(v);
          } else {
            Cf[(size_t)row * ldc + col] = v;
            cs += v;
            cq += v * v;
          }
        }
      }
    }
    if (!EPI) {
      // reduce over lg groups (lanes ^16, ^32 share the same column)
      cs += __shfl_xor(cs, 16); cq += __shfl_xor(cq, 16);
      cs += __shfl_xor(cs, 32); cq += __shfl_xor(cq, 32);
      if (lg == 0) {
        atomicAdd(&sums[col], cs);
        atomicAdd(&sums[D + col], cq);
      }
    }
  }
}

// ---------------- BatchNorm ----------------
__global__ void k_bnfinal(const float* __restrict__ sums, const float* __restrict__ sumsq,
                          const float* __restrict__ gamma, const float* __restrict__ beta,
                          float* __restrict__ scale, float* __restrict__ shift, int N) {
  int c = threadIdx.x;
  if (c >= D) return;
  float inv = 1.f / (float)N;
  float mean = sums[c] * inv;
  float var = sumsq[c] * inv - mean * mean;
  if (var < 0.f) var = 0.f;
  float sc = gamma[c] * rsqrtf(var + 1e-5f);
  scale[c] = sc;
  shift[c] = beta[c] - mean * sc;
}

__global__ void k_bnnorm(const float* __restrict__ h2, const float* __restrict__ scale,
                         const float* __restrict__ shift, float* __restrict__ h, int n4, int relu) {
  int i = blockIdx.x * blockDim.x + threadIdx.x;
  if (i >= n4) return;
  int base = i * 4;
  int d = base % D;
  f32x4 v = *(const f32x4*)(h2 + base);
#pragma unroll
  for (int k = 0; k < 4; ++k) {
    float xv = v[k] * scale[d + k] + shift[d + k];
    if (relu) xv = fmaxf(xv, 0.f);
    v[k] = xv;
  }
  *(f32x4*)(h + base) = v;
}

// ---------------- outputs ----------------
__global__ void k_pool(const float* __restrict__ h, const int* __restrict__ gs,
                       const int* __restrict__ gc, float* __restrict__ pooled) {
  int g = blockIdx.x, c = threadIdx.x;
  if (c >= D) return;
  int start = gs[g], cnt = gc[g];
  float s = 0.f;
  for (int i = 0; i < cnt; ++i) s += h[(size_t)(start + i) * D + c];
  int dv = cnt > 0 ? cnt : 1;
  pooled[(size_t)g * D + c] = s / (float)dv;
}

__global__ void k_nf(const float* __restrict__ h, const int* __restrict__ gs,
                     const int* __restrict__ gc, float* __restrict__ nf, float* __restrict__ mask) {
  int g = blockIdx.x;
  int start = gs[g], cnt = gc[g];
  int lim = cnt < MAXLEN ? cnt : MAXLEN;
  for (int idx = threadIdx.x; idx < MAXLEN * D; idx += 256) {
    int p = idx / D;
    int c = idx - p * D;
    float v = (p < lim) ? h[(size_t)(start + p) * D + c] : 0.f;
    nf[(size_t)g * (MAXLEN * D) + idx] = v;
  }
  if (threadIdx.x < MAXLEN) mask[(size_t)g * MAXLEN + threadIdx.x] = (threadIdx.x < lim) ? 1.f : 0.f;
}

extern "C" void kernel_launch(void* const* d_in, const int* in_sizes, int n_in,
                              void* d_out, int out_size, void* d_ws, size_t ws_size,
                              hipStream_t stream) {
  const int* x      = (const int*)d_in[0];
  const int* ei     = (const int*)d_in[1];   // [2][E]: src = ei, dst = ei+E
  const int* ea     = (const int*)d_in[2];   // [E][2]
  const int* batch  = (const int*)d_in[3];
  const float* xe1  = (const float*)d_in[5];
  const float* xe2  = (const float*)d_in[6];
  const float* ee1  = (const float*)d_in[7]; // [L][6][D]
  const float* ee2  = (const float*)d_in[8]; // [L][3][D]
  const float* W1   = (const float*)d_in[9];
  const float* b1   = (const float*)d_in[10];
  const float* W2   = (const float*)d_in[11];
  const float* b2   = (const float*)d_in[12];
  const float* gamma = (const float*)d_in[13];
  const float* beta  = (const float*)d_in[14];

  const int N = in_sizes[0] / 2;
  const int E = in_sizes[1] / 2;
  const int L = in_sizes[9] / (D * 2 * D);
  const int B = out_size / (D + MAXLEN * D + MAXLEN);

  char* ws = (char*)d_ws;
  size_t off = 0;
  auto alloc = [&](size_t bytes) -> void* {
    void* p = ws + off;
    off += (bytes + 255) & ~(size_t)255;
    return p;
  };
  float* h   = (float*)alloc((size_t)N * D * 4);
  float* h2  = (float*)alloc((size_t)N * D * 4);
  unsigned short* aggbf = (unsigned short*)alloc((size_t)N * K1P * 2);
  unsigned short* hid   = (unsigned short*)alloc((size_t)N * H1P * 2);
  unsigned short* W1tA = (unsigned short*)alloc((size_t)L * W1ROWS * K1P * 2);
  unsigned short* W2tA = (unsigned short*)alloc((size_t)L * W2ROWS * H1P * 2);
  float* ecomb = (float*)alloc((size_t)L * 18 * D * 4);
  int* cnt    = (int*)alloc((size_t)N * 4);
  int* cur    = (int*)alloc((size_t)N * 4);
  int* offs   = (int*)alloc((size_t)(N + 1) * 4);
  int* ssrc   = (int*)alloc((size_t)E * 4);
  int* seco   = (int*)alloc((size_t)E * 4);
  int* gc     = (int*)alloc((size_t)B * 4);
  int* gs     = (int*)alloc((size_t)(B + 1) * 4);
  float* sums  = (float*)alloc(2 * D * 4);  // sums | sumsq
  float* scale = (float*)alloc(2 * D * 4);  // scale | shift

  hipMemsetAsync(cnt, 0, (size_t)N * 4, stream);
  hipMemsetAsync(cur, 0, (size_t)N * 4, stream);
  hipMemsetAsync(gc, 0, (size_t)B * 4, stream);

  const int n4 = N * D / 4;
  k_embed<<<(n4 + 255) / 256, 256, 0, stream>>>(x, xe1, xe2, h, n4);
  k_padfill<<<(N * 28 + 255) / 256, 256, 0, stream>>>(aggbf, hid, N);
  k_count<<<(E + 255) / 256, 256, 0, stream>>>(ei + E, cnt, E);
  k_exscan<<<1, 1024, 0, stream>>>(cnt, offs, N);
  k_fill<<<(E + 255) / 256, 256, 0, stream>>>(ei, ei + E, ea, cur, offs, ssrc, seco, E);
  k_count<<<(N + 255) / 256, 256, 0, stream>>>(batch, gc, N);
  k_exscan<<<1, 1024, 0, stream>>>(gc, gs, B);
  k_ecomb<<<(L * 18 * D + 255) / 256, 256, 0, stream>>>(ee1, ee2, ecomb, L * 18 * D);
  for (int l = 0; l < L; ++l) {
    k_wconv<<<(W1ROWS * K1P + 255) / 256, 256, 0, stream>>>(
        W1 + (size_t)l * D * H1, W1tA + (size_t)l * W1ROWS * K1P, D, H1, K1P, W1ROWS * K1P);
    k_wconv<<<(W2ROWS * H1P + 255) / 256, 256, 0, stream>>>(
        W2 + (size_t)l * H1 * D, W2tA + (size_t)l * W2ROWS * H1P, H1, D, H1P, W2ROWS * H1P);
  }

  const int rowTiles = (N + 127) / 128;
  for (int l = 0; l < L; ++l) {
    k_agg<<<(N + 3) / 4, 256, 0, stream>>>(h, ssrc, seco, offs, ecomb + (size_t)l * 18 * D, aggbf, N);
    k_gemm<K1P, 1><<<5 * rowTiles, 256, 0, stream>>>(
        aggbf, W1tA + (size_t)l * W1ROWS * K1P, b1 + (size_t)l * H1, hid, nullptr, nullptr, N, H1, H1P, 5);
    hipMemsetAsync(sums, 0, 2 * D * 4, stream);
    k_gemm<H1P, 0><<<3 * rowTiles, 256, 0, stream>>>(
        hid, W2tA + (size_t)l * W2ROWS * H1P, b2 + (size_t)l * D, nullptr, h2, sums, N, D, D, 3);
    k_bnfinal<<<1, 320, 0, stream>>>(sums, sums + D, gamma + (size_t)l * D, beta + (size_t)l * D, scale, scale + D, N);
    k_bnnorm<<<(n4 + 255) / 256, 256, 0, stream>>>(h2, scale, scale + D, h, n4, (l != L - 1) ? 1 : 0);
  }

  float* out = (float*)d_out;
  float* out_pooled = out;
  float* out_nf = out + (size_t)B * D;
  float* out_mask = out + (size_t)B * D + (size_t)B * MAXLEN * D;
  k_pool<<<B, 320, 0, stream>>>(h, gs, gc, out_pooled);
  k_nf<<<B, 256, 0, stream>>>(h, gs, gc, out_nf, out_mask);
}